// Round 1
// baseline (18.028 us; speedup 1.0000x reference)
//
#include <hip/hip_runtime.h>
#include <cstdint>
#include <cstddef>

#define BB 64
#define CC 1024

// Kernel 1: parent[i] = max{ j < i : R[i,j] != 0 }  (ancestor chain indices are
// strictly decreasing by construction, so the largest proper ancestor is the parent).
// parent[0] = 0.
__global__ __launch_bounds__(64) void k_parent(const float* __restrict__ R,
                                               int* __restrict__ parent) {
    const int i = blockIdx.x;
    const int lane = threadIdx.x;
    int best = -1;
    const float* row = R + (size_t)i * CC;
    for (int j = lane; j < i; j += 64) {
        if (row[j] != 0.0f) best = j;  // j increases per lane -> last hit is the max
    }
    #pragma unroll
    for (int off = 32; off > 0; off >>= 1) {
        int o = __shfl_down(best, off);
        best = best > o ? best : o;
    }
    if (lane == 0) parent[i] = best < 0 ? 0 : best;
}

// Kernel 2: per-batch block. Computes x = sigmoid(h), probs (= x, since argmax of
// paths is provably the root node 0 and R[:,0] == 1), mcm via ancestor-chain walk,
// pv via ancestor-chain scatter with deterministic integer atomicMin, and the
// per-batch partial BCE sum.
__global__ __launch_bounds__(256) void k_main(const float* __restrict__ H,
                                              const float* __restrict__ Y,
                                              const int* __restrict__ parent,
                                              float* __restrict__ probs_out,
                                              float* __restrict__ partial) {
    __shared__ float xs[CC];
    __shared__ int   pvb[CC];
    __shared__ int   par[CC];
    __shared__ float redsum[4];

    const int b = blockIdx.x;
    const int t = threadIdx.x;

    const float* h = H + (size_t)b * CC;
    const float* y = Y + (size_t)b * CC;

    // --- load h (float4), sigmoid, init LDS ---
    float4 h4 = reinterpret_cast<const float4*>(h)[t];
    float xv[4];
    xv[0] = 1.0f / (1.0f + expf(-h4.x));
    xv[1] = 1.0f / (1.0f + expf(-h4.y));
    xv[2] = 1.0f / (1.0f + expf(-h4.z));
    xv[3] = 1.0f / (1.0f + expf(-h4.w));

    int4 p4 = reinterpret_cast<const int4*>(parent)[t];
    const int base = 4 * t;
    par[base + 0] = p4.x;
    par[base + 1] = p4.y;
    par[base + 2] = p4.z;
    par[base + 3] = p4.w;
    #pragma unroll
    for (int c = 0; c < 4; ++c) {
        xs[base + c]  = xv[c];
        pvb[base + c] = __float_as_int(xv[c]);
    }
    __syncthreads();

    // --- pv for root = min over ALL x (block reduction; avoids 1024-way atomic
    //     contention on pvb[0]) ---
    float lm = fminf(fminf(xv[0], xv[1]), fminf(xv[2], xv[3]));
    #pragma unroll
    for (int off = 32; off > 0; off >>= 1) lm = fminf(lm, __shfl_down(lm, off));
    if ((t & 63) == 0) atomicMin(&pvb[0], __float_as_int(lm));

    // --- ancestor-chain walks: mcm (register max) + pv scatter (atomicMin) ---
    float mcm[4];
    #pragma unroll
    for (int c = 0; c < 4; ++c) {
        const int i = base + c;
        float m = xv[c];
        if (i != 0) {
            const int xib = __float_as_int(xv[c]);
            int a = par[i];
            while (a != 0) {
                m = fmaxf(m, xs[a]);
                atomicMin(&pvb[a], xib);
                a = par[a];
            }
            m = fmaxf(m, xs[0]);
        }
        mcm[c] = m;
    }
    __syncthreads();

    // --- BCE terms + probs store ---
    float4 y4 = reinterpret_cast<const float4*>(y)[t];
    float yv[4] = {y4.x, y4.y, y4.z, y4.w};
    float acc = 0.0f;
    #pragma unroll
    for (int c = 0; c < 4; ++c) {
        const int i = base + c;
        const float pv = __int_as_float(pvb[i]);
        const float hs = (1.0f - yv[c]) * mcm[c] + pv * yv[c];
        const float lp  = fmaxf(logf(hs), -100.0f);
        const float l1p = fmaxf(log1pf(-hs), -100.0f);
        acc += yv[c] * lp + (1.0f - yv[c]) * l1p;
        probs_out[(size_t)b * CC + i] = xv[c];
    }

    // --- deterministic block reduction of the partial loss ---
    #pragma unroll
    for (int off = 32; off > 0; off >>= 1) acc += __shfl_down(acc, off);
    if ((t & 63) == 0) redsum[t >> 6] = acc;
    __syncthreads();
    if (t == 0) partial[b] = (redsum[0] + redsum[1]) + (redsum[2] + redsum[3]);
}

// Kernel 3: deterministic final reduction of the 64 per-batch partials.
__global__ __launch_bounds__(64) void k_final(const float* __restrict__ partial,
                                              float* __restrict__ out) {
    float v = partial[threadIdx.x];
    #pragma unroll
    for (int off = 32; off > 0; off >>= 1) v += __shfl_down(v, off);
    if (threadIdx.x == 0) out[0] = -v / (float)(BB * CC);
}

extern "C" void kernel_launch(void* const* d_in, const int* in_sizes, int n_in,
                              void* d_out, int out_size, void* d_ws, size_t ws_size,
                              hipStream_t stream) {
    const float* H = (const float*)d_in[0];  // (B, C) logits
    const float* Y = (const float*)d_in[1];  // (B, C) labels
    const float* R = (const float*)d_in[2];  // (C, C) ancestry

    float* out = (float*)d_out;              // [loss(1), probs(B*C)]
    int*   parent  = (int*)d_ws;             // C ints
    float* partial = (float*)d_ws + CC;      // B floats

    k_parent<<<CC, 64, 0, stream>>>(R, parent);
    k_main<<<BB, 256, 0, stream>>>(H, Y, parent, out + 1, partial);
    k_final<<<1, 64, 0, stream>>>(partial, out);
}